// Round 1
// baseline (1009.002 us; speedup 1.0000x reference)
//
#include <hip/hip_runtime.h>
#include <hip/hip_bf16.h>

// GCN forward: 3x (GEMM -> normalized scatter/gather aggregate -> ReLU),
// mean-pool by graph, 2-layer MLP classifier.
// Strategy: build CSR-by-dst once per launch, then gather-aggregate (no atomics
// in hot loops). norm = dinv[src]*dinv[dst] factored: dinv[src] folded into
// GEMM epilogue, dinv[dst]+bias+relu folded into aggregate epilogue.

__global__ void count_kernel(const int* __restrict__ dst, int* __restrict__ cnt, int E) {
    int e = blockIdx.x * 256 + threadIdx.x;
    if (e < E) atomicAdd(&cnt[dst[e]], 1);
}

__global__ void dinv_kernel(const int* __restrict__ cnt, float* __restrict__ dinv, int N) {
    int i = blockIdx.x * 256 + threadIdx.x;
    if (i < N) dinv[i] = rsqrtf((float)(cnt[i] + 1));  // +1 = self loop
}

// exclusive scan, 2048 elems/block
__global__ void scanA(const int* __restrict__ cnt, int* __restrict__ rp,
                      int* __restrict__ bs, int N) {
    __shared__ int lds[256];
    int t = threadIdx.x;
    int base = blockIdx.x * 2048 + t * 8;
    int v[8]; int tsum = 0;
#pragma unroll
    for (int i = 0; i < 8; i++) { int idx = base + i; int x = (idx < N) ? cnt[idx] : 0; v[i] = x; tsum += x; }
    lds[t] = tsum; __syncthreads();
#pragma unroll
    for (int d = 1; d < 256; d <<= 1) {
        int x = (t >= d) ? lds[t - d] : 0; __syncthreads();
        lds[t] += x; __syncthreads();
    }
    int run = lds[t] - tsum;
#pragma unroll
    for (int i = 0; i < 8; i++) { int idx = base + i; if (idx < N) rp[idx] = run; run += v[i]; }
    if (t == 255) bs[blockIdx.x] = lds[255];
}

__global__ void scanB(int* bs, int* rp, int NB, int N) {
    if (threadIdx.x == 0 && blockIdx.x == 0) {
        int run = 0;
        for (int i = 0; i < NB; i++) { int x = bs[i]; bs[i] = run; run += x; }
        rp[N] = run;
    }
}

__global__ void scanC(int* __restrict__ rp, const int* __restrict__ bs, int N) {
    int base = blockIdx.x * 2048 + threadIdx.x * 8;
    int add = bs[blockIdx.x];
#pragma unroll
    for (int i = 0; i < 8; i++) { int j = base + i; if (j < N) rp[j] += add; }
}

__global__ void fill_kernel(const int* __restrict__ src, const int* __restrict__ dst,
                            const int* __restrict__ rp, int* __restrict__ cursor,
                            int* __restrict__ csr, int E) {
    int e = blockIdx.x * 256 + threadIdx.x;
    if (e < E) {
        int d = dst[e];
        int pos = rp[d] + atomicAdd(&cursor[d], 1);
        csr[pos] = src[e];
    }
}

// G[row][j] = dinv[row] * sum_k X[row][k]*W[k][j]; wave=4 rows, lane=col j
template <int K>
__global__ __launch_bounds__(256) void gemm_dinv(const float* __restrict__ X,
                                                 const float* __restrict__ W,
                                                 const float* __restrict__ dinv,
                                                 float* __restrict__ G, int N) {
    __shared__ float Wl[K * 64];
    for (int i = threadIdx.x; i < K * 16; i += 256)
        ((float4*)Wl)[i] = ((const float4*)W)[i];
    __syncthreads();
    int lane = threadIdx.x & 63;
    int row0 = (blockIdx.x * 4 + (threadIdx.x >> 6)) * 4;
    row0 = __builtin_amdgcn_readfirstlane(row0);  // force scalar addressing for X
    if (row0 >= N) return;
    const float* x0 = X + (size_t)row0 * K;
    if (row0 + 4 <= N) {
        float a0 = 0.f, a1 = 0.f, a2 = 0.f, a3 = 0.f;
#pragma unroll 8
        for (int k = 0; k < K; k++) {
            float w = Wl[k * 64 + lane];
            a0 = fmaf(x0[k],         w, a0);
            a1 = fmaf(x0[K + k],     w, a1);
            a2 = fmaf(x0[2 * K + k], w, a2);
            a3 = fmaf(x0[3 * K + k], w, a3);
        }
        G[(size_t)row0 * 64 + lane]       = dinv[row0] * a0;
        G[(size_t)(row0 + 1) * 64 + lane] = dinv[row0 + 1] * a1;
        G[(size_t)(row0 + 2) * 64 + lane] = dinv[row0 + 2] * a2;
        G[(size_t)(row0 + 3) * 64 + lane] = dinv[row0 + 3] * a3;
    } else {
        for (int r = row0; r < N; r++) {
            float a = 0.f;
            for (int k = 0; k < K; k++) a = fmaf(X[(size_t)r * K + k], Wl[k * 64 + lane], a);
            G[(size_t)r * 64 + lane] = dinv[r] * a;
        }
    }
}

// H[node] = relu(dinv[node] * (G[node] + sum_{src in CSR[node]} G[src]) + b)
__global__ __launch_bounds__(256) void aggregate(const float* __restrict__ G,
                                                 const int* __restrict__ rp,
                                                 const int* __restrict__ csr,
                                                 const float* __restrict__ dinv,
                                                 const float* __restrict__ bias,
                                                 float* __restrict__ H, int N) {
    int node = blockIdx.x * 4 + (threadIdx.x >> 6);
    node = __builtin_amdgcn_readfirstlane(node);
    if (node >= N) return;
    int lane = threadIdx.x & 63;
    int beg = rp[node], end = rp[node + 1];
    float acc = G[(size_t)node * 64 + lane];  // self loop
    int e = beg;
    for (; e + 4 <= end; e += 4) {
        int s0 = csr[e], s1 = csr[e + 1], s2 = csr[e + 2], s3 = csr[e + 3];
        float v0 = G[(size_t)s0 * 64 + lane];
        float v1 = G[(size_t)s1 * 64 + lane];
        float v2 = G[(size_t)s2 * 64 + lane];
        float v3 = G[(size_t)s3 * 64 + lane];
        acc += v0; acc += v1; acc += v2; acc += v3;
    }
    for (; e < end; e++) acc += G[(size_t)csr[e] * 64 + lane];
    float v = dinv[node] * acc + bias[lane];
    H[(size_t)node * 64 + lane] = fmaxf(v, 0.f);
}

// batch is sorted: run-accumulate, flush on id change. wave = 128 nodes, lane = feat
__global__ __launch_bounds__(256) void pool_kernel(const float* __restrict__ H,
                                                   const int* __restrict__ batch,
                                                   float* __restrict__ sums,
                                                   int* __restrict__ gcnt, int N) {
    int wid = blockIdx.x * 4 + (threadIdx.x >> 6);
    int lane = threadIdx.x & 63;
    int s = wid * 128;
    if (s >= N) return;
    int e = min(s + 128, N);
    int cur = batch[s];
    float run = 0.f; int runc = 0;
    for (int n = s; n < e; n++) {
        int b = batch[n];
        if (b != cur) {
            atomicAdd(&sums[(size_t)cur * 64 + lane], run);
            if (lane == 0) atomicAdd(&gcnt[cur], runc);
            run = 0.f; runc = 0; cur = b;
        }
        run += H[(size_t)n * 64 + lane];
        runc++;
    }
    atomicAdd(&sums[(size_t)cur * 64 + lane], run);
    if (lane == 0) atomicAdd(&gcnt[cur], runc);
}

// per graph: pooled = sums/max(cnt,1); z = relu(pooled@Wc1+bc1); out = z@Wc2+bc2
__global__ __launch_bounds__(64) void classifier(const float* __restrict__ sums,
                                                 const int* __restrict__ gcnt,
                                                 const float* __restrict__ Wc1,
                                                 const float* __restrict__ bc1,
                                                 const float* __restrict__ Wc2,
                                                 const float* __restrict__ bc2,
                                                 float* __restrict__ out) {
    int g = blockIdx.x;
    int t = threadIdx.x;
    __shared__ float p[64];
    __shared__ float z[32];
    float cntf = fmaxf((float)gcnt[g], 1.0f);
    p[t] = sums[(size_t)g * 64 + t] / cntf;
    __syncthreads();
    if (t < 32) {
        float a = bc1[t];
        for (int f = 0; f < 64; f++) a = fmaf(p[f], Wc1[f * 32 + t], a);
        z[t] = fmaxf(a, 0.f);
    }
    __syncthreads();
    if (t < 10) {
        float a = bc2[t];
        for (int j = 0; j < 32; j++) a = fmaf(z[j], Wc2[j * 10 + t], a);
        out[(size_t)g * 10 + t] = a;
    }
}

extern "C" void kernel_launch(void* const* d_in, const int* in_sizes, int n_in,
                              void* d_out, int out_size, void* d_ws, size_t ws_size,
                              hipStream_t stream) {
    const float* x   = (const float*)d_in[0];
    const int*   ei  = (const int*)d_in[1];
    const int*   bat = (const int*)d_in[2];
    const float* W1  = (const float*)d_in[3];
    const float* b1  = (const float*)d_in[4];
    const float* W2  = (const float*)d_in[5];
    const float* b2  = (const float*)d_in[6];
    const float* W3  = (const float*)d_in[7];
    const float* b3  = (const float*)d_in[8];
    const float* Wc1 = (const float*)d_in[9];
    const float* bc1 = (const float*)d_in[10];
    const float* Wc2 = (const float*)d_in[11];
    const float* bc2 = (const float*)d_in[12];

    const int N  = in_sizes[0] / 128;
    const int E  = in_sizes[1] / 2;
    const int NG = out_size / 10;
    const int* srcp = ei;
    const int* dstp = ei + E;

    char* ws = (char*)d_ws;
    size_t off = 0;
    auto alloc = [&](size_t bytes) -> void* {
        void* p = ws + off;
        off += (bytes + 255) / 256 * 256;
        return p;
    };
    float* G    = (float*)alloc((size_t)N * 64 * 4);
    float* H    = (float*)alloc((size_t)N * 64 * 4);
    int*   csr  = (int*)alloc((size_t)E * 4);
    int*   rp   = (int*)alloc((size_t)(N + 1) * 4);
    int*   cnt  = (int*)alloc((size_t)N * 4);
    float* dinv = (float*)alloc((size_t)N * 4);
    int*   bs   = (int*)alloc(64 * 4);
    float* sums = (float*)alloc((size_t)NG * 64 * 4);
    int*   gcnt = (int*)alloc((size_t)NG * 4);
    (void)ws_size; (void)n_in;

    const int NB = (N + 2047) / 2048;

    hipMemsetAsync(cnt, 0, (size_t)N * 4, stream);
    count_kernel<<<(E + 255) / 256, 256, 0, stream>>>(dstp, cnt, E);
    dinv_kernel<<<(N + 255) / 256, 256, 0, stream>>>(cnt, dinv, N);
    scanA<<<NB, 256, 0, stream>>>(cnt, rp, bs, N);
    scanB<<<1, 64, 0, stream>>>(bs, rp, NB, N);
    scanC<<<NB, 256, 0, stream>>>(rp, bs, N);
    hipMemsetAsync(cnt, 0, (size_t)N * 4, stream);  // reuse as cursor
    fill_kernel<<<(E + 255) / 256, 256, 0, stream>>>(srcp, dstp, rp, cnt, csr, E);

    // layer 1 (K=128), layers 2,3 (K=64)
    gemm_dinv<128><<<(N + 15) / 16, 256, 0, stream>>>(x, W1, dinv, G, N);
    aggregate<<<(N + 3) / 4, 256, 0, stream>>>(G, rp, csr, dinv, b1, H, N);
    gemm_dinv<64><<<(N + 15) / 16, 256, 0, stream>>>(H, W2, dinv, G, N);
    aggregate<<<(N + 3) / 4, 256, 0, stream>>>(G, rp, csr, dinv, b2, H, N);
    gemm_dinv<64><<<(N + 15) / 16, 256, 0, stream>>>(H, W3, dinv, G, N);
    aggregate<<<(N + 3) / 4, 256, 0, stream>>>(G, rp, csr, dinv, b3, H, N);

    hipMemsetAsync(sums, 0, (size_t)NG * 64 * 4, stream);
    hipMemsetAsync(gcnt, 0, (size_t)NG * 4, stream);
    int waves = (N + 127) / 128;
    pool_kernel<<<(waves + 3) / 4, 256, 0, stream>>>(H, bat, sums, gcnt, N);
    classifier<<<NG, 64, 0, stream>>>(sums, gcnt, Wc1, bc1, Wc2, bc2, (float*)d_out);
}